// Round 3
// baseline (213.208 us; speedup 1.0000x reference)
//
#include <hip/hip_runtime.h>
#include <cstdint>

// Problem dims (fixed by the reference)
constexpr int B_  = 16;
constexpr int S_  = 1024;
constexpr int D_  = 1024;
constexpr int H_  = 8;
constexpr int NJ  = 24;    // H*K
constexpr int TR  = 64;    // output rows per block
constexpr int DD  = 128;   // reduction elements per chunk
constexpr int ND2 = DD / 2;
constexpr int NCH = D_ / DD;
constexpr int XPITCH = 66; // word pitch for X tile (bank-conflict-free, 8B-aligned pairs)

typedef _Float16 h2_t __attribute__((ext_vector_type(2)));

static __device__ __forceinline__ uint32_t packh2(float a, float b) {
  union { h2_t h; uint32_t u; } cv;
  cv.h[0] = (_Float16)a;
  cv.h[1] = (_Float16)b;
  return cv.u;
}

static __device__ __forceinline__ float dot2(uint32_t a, uint32_t b, float c) {
  union { uint32_t u; h2_t h; } ca, cb;
  ca.u = a; cb.u = b;
#if __has_builtin(__builtin_amdgcn_fdot2)
  return __builtin_amdgcn_fdot2(ca.h, cb.h, c, false);
#else
  return c + (float)ca.h[0] * (float)cb.h[0] + (float)ca.h[1] * (float)cb.h[1];
#endif
}

// One skinny GEMM: C (TR x 24) = X_tile (TR x 1024) @ W (1024 x 24)
// MODE 0: X = Q, W = Wq (shared), +bq, scatter-store into WfiltT[b][d][p]
// MODE 1: X = Key[b], W = WfiltT[b], plain store into U[b][t][p]
template <int MODE>
__global__ __launch_bounds__(256)
void skinny_gemm(const float* __restrict__ X, const float* __restrict__ W,
                 const float* __restrict__ bias, float* __restrict__ out)
{
  __shared__ uint32_t Xp[TR][XPITCH];  // f16-pair tile of X, [row][d2]
  __shared__ uint32_t Wp[ND2][NJ];     // f16-pair tile of W, [d2][j]

  const int b   = blockIdx.x >> 4;
  const int s0  = (blockIdx.x & 15) * TR;
  const int tid = threadIdx.x;
  const int cg  = tid & 7;   // col group: cols 3cg..3cg+2
  const int rg  = tid >> 3;  // row group: rows 2rg, 2rg+1

  const float* Xb = X + (size_t)b * S_ * D_;
  const float* Wb = (MODE == 0) ? W : (W + (size_t)b * D_ * NJ);

  // chunk-invariant staging coordinates
  int xrow[8], xc4[8];
#pragma unroll
  for (int p = 0; p < 8; ++p) {
    int t4 = p * 256 + tid;
    xrow[p] = t4 >> 5;   // 32 float4 per row of 128 floats
    xc4[p]  = t4 & 31;
  }
  int wd2[6], wj[6];
#pragma unroll
  for (int i = 0; i < 6; ++i) {
    int idx = i * 256 + tid;  // [0,1536)
    wd2[i] = idx / 24;
    wj[i]  = idx % 24;
  }

  float4 xr[8];
  float  wra[6], wrb[6];

  auto stage_load = [&](int d0) {
#pragma unroll
    for (int p = 0; p < 8; ++p)
      xr[p] = *(const float4*)(Xb + (size_t)(s0 + xrow[p]) * D_ + d0 + xc4[p] * 4);
#pragma unroll
    for (int i = 0; i < 6; ++i) {
      const float* wp = Wb + (size_t)(d0 + 2 * wd2[i]) * NJ + wj[i];
      wra[i] = wp[0];
      wrb[i] = wp[NJ];
    }
  };
  auto stage_write = [&]() {
#pragma unroll
    for (int p = 0; p < 8; ++p) {
      uint32_t lo = packh2(xr[p].x, xr[p].y);
      uint32_t hi = packh2(xr[p].z, xr[p].w);
      *(uint2*)&Xp[xrow[p]][2 * xc4[p]] = make_uint2(lo, hi);  // 8B-aligned (even word)
    }
#pragma unroll
    for (int i = 0; i < 6; ++i)
      Wp[wd2[i]][wj[i]] = packh2(wra[i], wrb[i]);  // addr == flat idx: conflict-free
  };

  float acc[2][3] = {{0.f, 0.f, 0.f}, {0.f, 0.f, 0.f}};

  stage_load(0);
  stage_write();
  __syncthreads();

  for (int k = 0; k < NCH; ++k) {
    if (k + 1 < NCH) stage_load((k + 1) * DD);  // prefetch next chunk into regs
#pragma unroll 8
    for (int d2 = 0; d2 < ND2; ++d2) {
      uint32_t x0 = Xp[2 * rg][d2];
      uint32_t x1 = Xp[2 * rg + 1][d2];
      uint32_t w0 = Wp[d2][3 * cg];
      uint32_t w1 = Wp[d2][3 * cg + 1];
      uint32_t w2 = Wp[d2][3 * cg + 2];
      acc[0][0] = dot2(x0, w0, acc[0][0]);
      acc[0][1] = dot2(x0, w1, acc[0][1]);
      acc[0][2] = dot2(x0, w2, acc[0][2]);
      acc[1][0] = dot2(x1, w0, acc[1][0]);
      acc[1][1] = dot2(x1, w1, acc[1][1]);
      acc[1][2] = dot2(x1, w2, acc[1][2]);
    }
    __syncthreads();
    if (k + 1 < NCH) {
      stage_write();
      __syncthreads();
    }
  }

  if (MODE == 0) {
    // Lin[s, j] -> WfiltT[b][d][p]; h=s>>7, d=(s&127)*8 + j/3, p=3h + j%3
#pragma unroll
    for (int r = 0; r < 2; ++r) {
      int s = s0 + 2 * rg + r;
      int h = s >> 7;
      int d = (s & 127) * 8 + cg;  // per-thread cols are j=3cg+i -> j/3 == cg
      float* dst = out + ((size_t)b * D_ + d) * NJ + h * 3;
#pragma unroll
      for (int i = 0; i < 3; ++i)
        dst[i] = acc[r][i] + bias[3 * cg + i];
    }
  } else {
#pragma unroll
    for (int r = 0; r < 2; ++r) {
      int t = s0 + 2 * rg + r;
      float* dst = out + ((size_t)b * S_ + t) * NJ + 3 * cg;
#pragma unroll
      for (int i = 0; i < 3; ++i)
        dst[i] = acc[r][i];
    }
  }
}

// out[b,h,s] = U[b,s-1,3h] + U[b,s,3h+1] + U[b,s+1,3h+2] + conv_bias[h]
__global__ __launch_bounds__(256)
void conv_combine(const float* __restrict__ U, const float* __restrict__ cbias,
                  float* __restrict__ out)
{
  __shared__ float Ul[258][25];  // rows t = s0-1 .. s0+256, pitch 25 (conflict-free)
  const int b   = blockIdx.x >> 2;
  const int s0  = (blockIdx.x & 3) * 256;
  const int tid = threadIdx.x;

#pragma unroll
  for (int i = 0; i < 25; ++i) {
    int idx = i * 256 + tid;
    if (idx < 258 * 24) {
      int row = idx / 24;
      int p   = idx % 24;
      int t   = s0 - 1 + row;
      float v = 0.f;
      if (t >= 0 && t < S_) v = U[((size_t)b * S_ + t) * NJ + p];
      Ul[row][p] = v;
    }
  }
  __syncthreads();

  const int s = s0 + tid;
#pragma unroll
  for (int h = 0; h < H_; ++h) {
    float v = Ul[tid][3 * h] + Ul[tid + 1][3 * h + 1] + Ul[tid + 2][3 * h + 2] + cbias[h];
    out[((size_t)(b * H_ + h)) * S_ + s] = v;
  }
}

extern "C" void kernel_launch(void* const* d_in, const int* in_sizes, int n_in,
                              void* d_out, int out_size, void* d_ws, size_t ws_size,
                              hipStream_t stream)
{
  const float* Q   = (const float*)d_in[0];  // (B,S,D)
  const float* Key = (const float*)d_in[1];  // (B,S,D)
  // d_in[2] value_sequences: unused by the reference forward
  const float* Wq  = (const float*)d_in[3];  // (D, 24)
  const float* bq  = (const float*)d_in[4];  // (24,)
  const float* cb  = (const float*)d_in[5];  // (8,)
  // d_in[6] key_value_sequence_lengths: unused by the reference forward
  float* out = (float*)d_out;                // (B,H,S) fp32

  float* Wfilt = (float*)d_ws;                   // B*D*24 f32 = 1.5 MB
  float* U     = Wfilt + (size_t)B_ * D_ * NJ;   // B*S*24 f32 = 1.5 MB

  skinny_gemm<0><<<B_ * (S_ / TR), 256, 0, stream>>>(Q, Wq, bq, Wfilt);
  skinny_gemm<1><<<B_ * (S_ / TR), 256, 0, stream>>>(Key, Wfilt, nullptr, U);
  conv_combine<<<B_ * (S_ / 256), 256, 0, stream>>>(U, cb, out);
}

// Round 4
// 197.648 us; speedup vs baseline: 1.0787x; 1.0787x over previous
//
#include <hip/hip_runtime.h>
#include <cstdint>

// Problem dims (fixed by the reference)
constexpr int B_ = 16, S_ = 1024, D_ = 1024, H_ = 8, NJ = 24;  // NJ = H*K
constexpr int BM     = 64;          // output rows per block (4 waves x 16)
constexpr int KC     = 128;         // k elements per chunk
constexpr int KHALF  = 512;         // k per block (K-split 2)
constexpr int NCHUNK = KHALF / KC;  // 4
constexpr int XPIT   = 136;         // f16 pitch: 272B rows -> 4-bank stagger, 16B aligned

typedef _Float16 f16x8 __attribute__((ext_vector_type(8)));
typedef float    f32x4 __attribute__((ext_vector_type(4)));

static __device__ __forceinline__ uint32_t packh2(float a, float b) {
  union { _Float16 h[2]; uint32_t u; } cv;
  cv.h[0] = (_Float16)a;  // v_cvt_f16_f32 (RTN) — same rounding as the passing baseline
  cv.h[1] = (_Float16)b;
  return cv.u;
}

// C[64 rows x 24 cols] += X[64, K-half] @ W[K-half, 24] via mfma_f32_16x16x32_f16.
// MODE 0: X=Q, W=Wq (+bq on half 0), scatter-store partial into Wfilt layout [b][d][p]
// MODE 1: X=Key, W=Pa+Pb (Wfilt partial pair summed during staging), store U partial [b][t][p]
template <int MODE>
__global__ __launch_bounds__(256, 2)
void gemm16(const float* __restrict__ X, const float* __restrict__ Wsrc0,
            const float* __restrict__ Wsrc1, const float* __restrict__ bias,
            float* __restrict__ P0, float* __restrict__ P1)
{
  __shared__ alignas(16) _Float16 Xt[BM][XPIT];  // A tile, f16
  __shared__ alignas(16) _Float16 Wt[32][XPIT];  // B tile transposed [col][k], cols 24-31 zero

  const int tid  = threadIdx.x;
  const int bid  = blockIdx.x;
  const int half = bid & 1;          // K-split half
  const int rt   = (bid >> 1) & 15;  // row tile within batch
  const int b    = bid >> 5;         // batch
  const int s0   = rt * BM;
  const int k0g  = half * KHALF;

  const float* Xb = X + ((size_t)b * S_ + s0) * D_;
  const float* Wb0 = (MODE == 0) ? Wsrc0 : Wsrc0 + (size_t)b * D_ * NJ;
  const float* Wb1 = (MODE == 0) ? nullptr : Wsrc1 + (size_t)b * D_ * NJ;

  float4 xr[8];
  float  wA0[6], wA1[6];
  float  wB0[6], wB1[6];

  auto stage_load = [&](int kc) {
    const int k0 = k0g + kc * KC;
#pragma unroll
    for (int it = 0; it < 8; ++it) {  // 64 rows x 128 k f32, fully coalesced (1KB/instr)
      int f4 = it * 256 + tid;
      xr[it] = *(const float4*)(Xb + (size_t)(f4 >> 5) * D_ + k0 + (f4 & 31) * 4);
    }
#pragma unroll
    for (int it = 0; it < 6; ++it) {  // 128 k x 24 j, as 64 k-pairs x 24
      int flat = it * 256 + tid;      // [0,1536)
      int kp = flat / 24, j = flat - kp * 24;
      const float* p0 = Wb0 + (size_t)(k0 + 2 * kp) * NJ + j;
      wA0[it] = p0[0]; wA1[it] = p0[NJ];
      if (MODE == 1) {
        const float* p1 = Wb1 + (size_t)(k0 + 2 * kp) * NJ + j;
        wB0[it] = p1[0]; wB1[it] = p1[NJ];
      }
    }
  };
  auto stage_write = [&]() {
#pragma unroll
    for (int it = 0; it < 8; ++it) {
      int f4 = it * 256 + tid;
      int row = f4 >> 5, c4 = f4 & 31;
      uint2 v = make_uint2(packh2(xr[it].x, xr[it].y), packh2(xr[it].z, xr[it].w));
      *(uint2*)&Xt[row][c4 * 4] = v;  // 8B aligned (272*row + 8*c4)
    }
#pragma unroll
    for (int it = 0; it < 6; ++it) {
      int flat = it * 256 + tid;
      int kp = flat / 24, j = flat - kp * 24;
      float a = wA0[it], c = wA1[it];
      if (MODE == 1) { a += wB0[it]; c += wB1[it]; }  // fold Wfilt partial combine
      *(uint32_t*)&Wt[j][2 * kp] = packh2(a, c);      // transposed store [col][k]
    }
  };

  // MFMA lane geometry (16x16x32: A row=l&15 k=(l>>4)*8+j ; B col=l&15 ; D col=l&15 row=(l>>4)*4+r)
  const int lane = tid & 63, w = tid >> 6;
  const int arow = 16 * w + (lane & 15);
  const int kgrp = ((lane >> 4) & 3) * 8;
  const int colA = lane & 15;

  f32x4 acc0 = {0.f, 0.f, 0.f, 0.f};  // cols 0-15
  f32x4 acc1 = {0.f, 0.f, 0.f, 0.f};  // cols 16-31 (24-31 pad, never stored)

  // zero pad cols 24..31 of Wt once (staging never touches them)
  for (int idx = tid; idx < 544; idx += 256) ((uint32_t*)&Wt[24][0])[idx] = 0u;

  stage_load(0);
  stage_write();
  __syncthreads();

  for (int c = 0; c < NCHUNK; ++c) {
    if (c + 1 < NCHUNK) stage_load(c + 1);  // prefetch next chunk into regs
#pragma unroll
    for (int ks = 0; ks < KC / 32; ++ks) {
      f16x8 a  = *(const f16x8*)&Xt[arow][ks * 32 + kgrp];
      f16x8 b0 = *(const f16x8*)&Wt[colA][ks * 32 + kgrp];
      f16x8 b1 = *(const f16x8*)&Wt[colA + 16][ks * 32 + kgrp];
      acc0 = __builtin_amdgcn_mfma_f32_16x16x32_f16(a, b0, acc0, 0, 0, 0);
      acc1 = __builtin_amdgcn_mfma_f32_16x16x32_f16(a, b1, acc1, 0, 0, 0);
    }
    __syncthreads();
    if (c + 1 < NCHUNK) { stage_write(); __syncthreads(); }
  }

  float* Pdst = (half == 0) ? P0 : P1;
  const int rbase = s0 + 16 * w + ((lane >> 4) & 3) * 4;

  if (MODE == 0) {
    // Lin[s,j] -> Wfilt[b][d][p]: h=s>>7, d=8*(s&127)+j/3, p=3h+j%3
    const int j0 = colA, j1 = 16 + colA;
    const int jd0 = j0 / 3, jm0 = j0 - 3 * jd0;
    const int jd1 = j1 / 3, jm1 = j1 - 3 * jd1;
    const float bj0 = (half == 0) ? bias[j0] : 0.f;          // bias only in half 0
    const float bj1 = (half == 0 && colA < 8) ? bias[j1] : 0.f;
    float* Pb_ = Pdst + (size_t)b * D_ * NJ;
#pragma unroll
    for (int r = 0; r < 4; ++r) {
      int s = rbase + r;
      int h = s >> 7, sl = s & 127;
      Pb_[(size_t)(sl * 8 + jd0) * NJ + 3 * h + jm0] = acc0[r] + bj0;
      if (colA < 8)
        Pb_[(size_t)(sl * 8 + jd1) * NJ + 3 * h + jm1] = acc1[r] + bj1;
    }
  } else {
    float* Ub_ = Pdst + (size_t)b * S_ * NJ;
#pragma unroll
    for (int r = 0; r < 4; ++r) {
      int t = rbase + r;
      Ub_[(size_t)t * NJ + colA] = acc0[r];
      if (colA < 8) Ub_[(size_t)t * NJ + 16 + colA] = acc1[r];
    }
  }
}

// out[b,h,s] = (Ua+Ub)[b,s-1,3h] + (Ua+Ub)[b,s,3h+1] + (Ua+Ub)[b,s+1,3h+2] + conv_bias[h]
__global__ __launch_bounds__(256)
void conv_combine(const float* __restrict__ Ua, const float* __restrict__ Ub,
                  const float* __restrict__ cbias, float* __restrict__ out)
{
  __shared__ float Ul[258][25];  // rows t = s0-1 .. s0+256, pitch 25 (conflict-free)
  const int b   = blockIdx.x >> 2;
  const int s0  = (blockIdx.x & 3) * 256;
  const int tid = threadIdx.x;

#pragma unroll
  for (int i = 0; i < 25; ++i) {
    int idx = i * 256 + tid;
    if (idx < 258 * 24) {
      int row = idx / 24;
      int p   = idx % 24;
      int t   = s0 - 1 + row;
      float v = 0.f;
      if (t >= 0 && t < S_) {
        size_t a = ((size_t)b * S_ + t) * NJ + p;
        v = Ua[a] + Ub[a];
      }
      Ul[row][p] = v;
    }
  }
  __syncthreads();

  const int s = s0 + tid;
#pragma unroll
  for (int h = 0; h < H_; ++h) {
    float v = Ul[tid][3 * h] + Ul[tid + 1][3 * h + 1] + Ul[tid + 2][3 * h + 2] + cbias[h];
    out[((size_t)(b * H_ + h)) * S_ + s] = v;
  }
}

extern "C" void kernel_launch(void* const* d_in, const int* in_sizes, int n_in,
                              void* d_out, int out_size, void* d_ws, size_t ws_size,
                              hipStream_t stream)
{
  const float* Q   = (const float*)d_in[0];  // (B,S,D)
  const float* Key = (const float*)d_in[1];  // (B,S,D)
  // d_in[2] value_sequences: unused by the reference forward
  const float* Wq  = (const float*)d_in[3];  // (D, 24)
  const float* bq  = (const float*)d_in[4];  // (24,)
  const float* cb  = (const float*)d_in[5];  // (8,)
  // d_in[6] key_value_sequence_lengths: unused by the reference forward
  float* out = (float*)d_out;                // (B,H,S) fp32

  float* Pa = (float*)d_ws;                  // Wfilt partial (K half 0), [b][d][24]
  float* Pb = Pa + (size_t)B_ * D_ * NJ;     // Wfilt partial (K half 1)
  float* Ua = Pb + (size_t)B_ * D_ * NJ;     // U partial (d half 0), [b][t][24]
  float* Ub = Ua + (size_t)B_ * S_ * NJ;     // U partial (d half 1)

  gemm16<0><<<512, 256, 0, stream>>>(Q,   Wq, nullptr, bq, Pa, Pb);
  gemm16<1><<<512, 256, 0, stream>>>(Key, Pa, Pb, nullptr, Ua, Ub);
  conv_combine<<<B_ * (S_ / 256), 256, 0, stream>>>(Ua, Ub, cb, out);
}